// Round 13
// baseline (128.847 us; speedup 1.0000x reference)
//
#include <hip/hip_runtime.h>
#include <stdint.h>

// B=32, L=128, A=64, C=128, KT=3.  scale = sqrt(190), inv = 1/sqrt(190).
// Linearity: agent_sum(y) = conv(sum_a x) + 64*bias ; time_sum(y) = W0*(S-x127)+W1*S+W2*(S-x0)+128*bias.
// Conv: rolling window, 8 t's per block, ring of 4 one-t slabs; stages each x row ONCE.

typedef __attribute__((ext_vector_type(8))) short bf16x8;
typedef __attribute__((ext_vector_type(4))) float f32x4;

__device__ __forceinline__ uint32_t f2bf(float f) {
    union { float f; uint32_t u; } v; v.f = f;
    return (v.u + 0x7FFFu + ((v.u >> 16) & 1u)) >> 16;  // RNE
}
__device__ __forceinline__ float bf2f(uint32_t h) {
    union { uint32_t u; float f; } v; v.u = h << 16; return v.f;
}
__device__ __forceinline__ uint32_t pk2(float lo, float hi) {
    return f2bf(lo) | (f2bf(hi) << 16);
}

// red: block (b,g) g<16 covers 8 t's.  xa16[b][t+1][ci] = bf16(sum_a x) (+ zero guards),
// xt_part[b][g][a][ci] = sum_{t in g} x.  Blocks >= 512 pack W into MFMA B-fragment order.
__global__ __launch_bounds__(256) void red_kernel(
    const float* __restrict__ x, uint16_t* __restrict__ xa16, float* __restrict__ xt_part,
    const float* __restrict__ W, uint16_t* __restrict__ wp)
{
    const int tid = threadIdx.x;
    const int bid = blockIdx.x;
    if (bid >= 512) {                        // wpack: 192 blocks
        int o = (bid - 512) * 256 + tid;     // 49152 exact
        int i = o & 7, lane = (o >> 3) & 63, nt = (o >> 9) & 7, ks = (o >> 12) & 3, d = o >> 14;
        int ci = ks * 32 + (lane >> 4) * 8 + i;
        int co = nt * 16 + (lane & 15);
        wp[o] = (uint16_t)f2bf(W[(co * 128 + ci) * 3 + d]);
        return;
    }
    const int b = bid >> 4, g = bid & 15;
    const int ci8 = (tid & 15) * 8, ag = tid >> 4;      // a = ag*4 + r
    __shared__ float red[16][128];

    float xtl[4][8];
    #pragma unroll
    for (int r = 0; r < 4; ++r)
        #pragma unroll
        for (int j = 0; j < 8; ++j) xtl[r][j] = 0.f;

    #pragma unroll
    for (int ti = 0; ti < 8; ++ti) {
        const int t = g * 8 + ti;
        const float* xr = x + ((size_t)(b * 128 + t) * 64) * 128;
        float s[8];
        #pragma unroll
        for (int j = 0; j < 8; ++j) s[j] = 0.f;
        #pragma unroll
        for (int r = 0; r < 4; ++r) {
            const int a = ag * 4 + r;
            const float4 v0 = *(const float4*)(xr + a * 128 + ci8);
            const float4 v1 = *(const float4*)(xr + a * 128 + ci8 + 4);
            s[0] += v0.x; s[1] += v0.y; s[2] += v0.z; s[3] += v0.w;
            s[4] += v1.x; s[5] += v1.y; s[6] += v1.z; s[7] += v1.w;
            xtl[r][0] += v0.x; xtl[r][1] += v0.y; xtl[r][2] += v0.z; xtl[r][3] += v0.w;
            xtl[r][4] += v1.x; xtl[r][5] += v1.y; xtl[r][6] += v1.z; xtl[r][7] += v1.w;
        }
        *(float4*)&red[ag][ci8]     = make_float4(s[0], s[1], s[2], s[3]);
        *(float4*)&red[ag][ci8 + 4] = make_float4(s[4], s[5], s[6], s[7]);
        __syncthreads();
        if (tid < 128) {
            float v = 0.f;
            #pragma unroll
            for (int i = 0; i < 16; ++i) v += red[i][tid];
            xa16[(size_t)(b * 130 + t + 1) * 128 + tid] = (uint16_t)f2bf(v);
        }
        __syncthreads();
    }
    if (g == 0 && tid < 16)
        *(uint4*)(xa16 + (size_t)(b * 130) * 128 + tid * 8) = make_uint4(0, 0, 0, 0);
    if (g == 15 && tid < 16)
        *(uint4*)(xa16 + (size_t)(b * 130 + 129) * 128 + tid * 8) = make_uint4(0, 0, 0, 0);
    #pragma unroll
    for (int r = 0; r < 4; ++r) {
        float* p = xt_part + (((size_t)(b * 16 + g) * 64 + ag * 4 + r) * 128) + ci8;
        *(float4*)p       = make_float4(xtl[r][0], xtl[r][1], xtl[r][2], xtl[r][3]);
        *(float4*)(p + 4) = make_float4(xtl[r][4], xtl[r][5], xtl[r][6], xtl[r][7]);
    }
}

// xt[row][ci] = sum_g xt_part[b][g][a][ci]   (row = b*64+a)
__global__ __launch_bounds__(256) void xtr_kernel(
    const float* __restrict__ xt_part, float* __restrict__ xt)
{
    const int idx = blockIdx.x * 256 + threadIdx.x;   // 128 blocks: 32768 = 2048 x 16
    const int row = idx >> 4, ci8 = (idx & 15) * 8;
    const int b = row >> 6, a = row & 63;
    float s[8];
    #pragma unroll
    for (int j = 0; j < 8; ++j) s[j] = 0.f;
    #pragma unroll
    for (int g2 = 0; g2 < 16; ++g2) {
        const float* p = xt_part + (((size_t)(b * 16 + g2) * 64 + a) * 128) + ci8;
        const float4 v0 = *(const float4*)p;
        const float4 v1 = *(const float4*)(p + 4);
        s[0] += v0.x; s[1] += v0.y; s[2] += v0.z; s[3] += v0.w;
        s[4] += v1.x; s[5] += v1.y; s[6] += v1.z; s[7] += v1.w;
    }
    float* q = xt + (size_t)row * 128 + ci8;
    *(float4*)q       = make_float4(s[0], s[1], s[2], s[3]);
    *(float4*)(q + 4) = make_float4(s[4], s[5], s[6], s[7]);
}

// Combined small-GEMM kernel: blocks 0..31 -> asum (per b), blocks 32..47 -> tsum (128 rows each).
__global__ __launch_bounds__(256, 2) void sums_kernel(
    const uint16_t* __restrict__ xa16, const float* __restrict__ xt,
    const float* __restrict__ x, const uint16_t* __restrict__ wp,
    const float* __restrict__ bias, float* __restrict__ asum, float* __restrict__ tsum)
{
    __shared__ __align__(16) uint16_t slab[130 * 128];
    const int tid = threadIdx.x;
    const int lane = tid & 63, wid = tid >> 6;
    const int wm = wid >> 1, wn = wid & 1;
    const int lr = lane & 15, lg = lane >> 4;
    f32x4 acc[4][4];
    #pragma unroll
    for (int mi = 0; mi < 4; ++mi)
        #pragma unroll
        for (int ni = 0; ni < 4; ++ni) acc[mi][ni] = (f32x4)0.f;

    if (blockIdx.x < 32) {
        const int b = blockIdx.x;
        #pragma unroll
        for (int it = 0; it < 9; ++it) {
            const int gg = it * 256 + tid;
            if (gg < 2080) {
                const int row = gg >> 4, sp = gg & 15;
                const int sl = sp ^ (row & 7);
                *(uint4*)(slab + gg * 8) =
                    *(const uint4*)(xa16 + (size_t)(b * 130 + row) * 128 + sl * 8);
            }
        }
        __syncthreads();
        #pragma unroll
        for (int g = 0; g < 4; ++g)
            #pragma unroll
            for (int d = 0; d < 3; ++d) {
                bf16x8 bq[4], af[4];
                #pragma unroll
                for (int ni = 0; ni < 4; ++ni)
                    bq[ni] = *(const bf16x8*)(wp + (size_t)((((d * 4 + g) * 8) + wn * 4 + ni) * 64 + lane) * 8);
                #pragma unroll
                for (int mi = 0; mi < 4; ++mi) {
                    const int row = wm * 64 + mi * 16 + lr + d;
                    af[mi] = *(const bf16x8*)(slab + row * 128 + ((g * 4 + lg) ^ (row & 7)) * 8);
                }
                #pragma unroll
                for (int mi = 0; mi < 4; ++mi)
                    #pragma unroll
                    for (int ni = 0; ni < 4; ++ni)
                        acc[mi][ni] = __builtin_amdgcn_mfma_f32_16x16x32_bf16(af[mi], bq[ni], acc[mi][ni], 0, 0, 0);
            }
        #pragma unroll
        for (int ni = 0; ni < 4; ++ni) {
            const int col = wn * 64 + ni * 16 + lr;
            const float bv = 64.f * bias[col];
            #pragma unroll
            for (int mi = 0; mi < 4; ++mi)
                #pragma unroll
                for (int j = 0; j < 4; ++j) {
                    const int t = wm * 64 + mi * 16 + lg * 4 + j;
                    asum[((size_t)b * 128 + t) * 128 + col] = acc[mi][ni][j] + bv;
                }
        }
        return;
    }

    const int bid = blockIdx.x - 32;
    const int r = tid >> 1, h = tid & 1;
    const int grow = bid * 128 + r, sb = grow >> 6, sa = grow & 63;
    #pragma unroll
    for (int d = 0; d < 3; ++d) {
        {
            const float* Sp = xt + (size_t)grow * 128 + h * 64;
            const float* Ep = x + ((size_t)((sb * 128 + (d == 0 ? 127 : 0)) * 64 + sa)) * 128 + h * 64;
            #pragma unroll
            for (int k = 0; k < 8; ++k) {
                float4 f0 = *(const float4*)(Sp + k * 8);
                float4 f1 = *(const float4*)(Sp + k * 8 + 4);
                if (d != 1) {
                    const float4 e0 = *(const float4*)(Ep + k * 8);
                    const float4 e1 = *(const float4*)(Ep + k * 8 + 4);
                    f0.x -= e0.x; f0.y -= e0.y; f0.z -= e0.z; f0.w -= e0.w;
                    f1.x -= e1.x; f1.y -= e1.y; f1.z -= e1.z; f1.w -= e1.w;
                }
                uint4 o;
                o.x = pk2(f0.x, f0.y); o.y = pk2(f0.z, f0.w);
                o.z = pk2(f1.x, f1.y); o.w = pk2(f1.z, f1.w);
                const int sl = h * 8 + k;
                *(uint4*)(slab + r * 128 + (sl ^ (r & 7)) * 8) = o;
            }
        }
        __syncthreads();
        #pragma unroll
        for (int g = 0; g < 4; ++g) {
            bf16x8 bq[4], af[4];
            #pragma unroll
            for (int ni = 0; ni < 4; ++ni)
                bq[ni] = *(const bf16x8*)(wp + (size_t)((((d * 4 + g) * 8) + wn * 4 + ni) * 64 + lane) * 8);
            #pragma unroll
            for (int mi = 0; mi < 4; ++mi) {
                const int row = wm * 64 + mi * 16 + lr;
                af[mi] = *(const bf16x8*)(slab + row * 128 + ((g * 4 + lg) ^ (row & 7)) * 8);
            }
            #pragma unroll
            for (int mi = 0; mi < 4; ++mi)
                #pragma unroll
                for (int ni = 0; ni < 4; ++ni)
                    acc[mi][ni] = __builtin_amdgcn_mfma_f32_16x16x32_bf16(af[mi], bq[ni], acc[mi][ni], 0, 0, 0);
        }
        __syncthreads();
    }
    #pragma unroll
    for (int ni = 0; ni < 4; ++ni) {
        const int col = wn * 64 + ni * 16 + lr;
        const float bv = 128.f * bias[col];
        #pragma unroll
        for (int mi = 0; mi < 4; ++mi)
            #pragma unroll
            for (int j = 0; j < 4; ++j) {
                const int rg = bid * 128 + wm * 64 + mi * 16 + lg * 4 + j;
                tsum[(size_t)rg * 128 + col] = acc[mi][ni][j] + bv;
            }
    }
}

// Rolling-window conv: one block per (b, 8-t group), 512 threads / 8 waves (16-co slices).
// Ring of 4 one-t slabs (64a x 128ci bf16 = 16 KB each) + 16 KB y-bounce = 80 KB -> 2 blocks/CU.
// Per t: stage ONE new slab (T14 issue-early/write-late), 48 MFMA/wave, fused epilogue.
__global__ __launch_bounds__(512, 4) void conv_kernel(
    const float* __restrict__ x, const uint16_t* __restrict__ wp,
    const float* __restrict__ bias, const float* __restrict__ asum,
    const float* __restrict__ tsum, float* __restrict__ out)
{
    __shared__ __align__(16) uint16_t ring[4][8192];   // slab τ at slot (τ - t0 + 1) & 3
    __shared__ __align__(16) uint16_t yb[8192];        // y bounce

    const int tid = threadIdx.x;
    const int bid = blockIdx.x;              // b*16 + tg
    const int b = bid >> 4, t0 = (bid & 15) * 8;
    const int lane = tid & 63, wid = tid >> 6;
    const int lr = lane & 15, lg = lane >> 4;

    // staging decode: thread -> (row=a, 32B granule-pair), linear LDS dest, pre-swizzled src
    const int srow = tid >> 3, pair = tid & 7, r7 = srow & 7;
    const int sgbase = ((2 * pair) ^ r7) & ~1;         // even logical granule of the pair
    const bool sswap = (r7 & 1);
    const float* xsrc0 = x + ((size_t)(b * 128) * 64 + srow) * 128 + sgbase * 8;
    const int sdst = tid * 16;                         // element offset in slab

#define STAGE_LOAD(tau, h) do {                                                \
    if ((unsigned)(tau) < 128u) {                                              \
        const float* s_ = xsrc0 + (size_t)(tau) * 8192;                        \
        h[0] = *(const float4*)s_;       h[1] = *(const float4*)(s_ + 4);      \
        h[2] = *(const float4*)(s_ + 8); h[3] = *(const float4*)(s_ + 12);     \
    } else {                                                                   \
        h[0] = h[1] = h[2] = h[3] = make_float4(0.f, 0.f, 0.f, 0.f);           \
    } } while (0)

#define STAGE_WRITE(slot, h) do {                                              \
    uint4 lo_, hi_;                                                            \
    lo_.x = pk2(h[0].x, h[0].y); lo_.y = pk2(h[0].z, h[0].w);                  \
    lo_.z = pk2(h[1].x, h[1].y); lo_.w = pk2(h[1].z, h[1].w);                  \
    hi_.x = pk2(h[2].x, h[2].y); hi_.y = pk2(h[2].z, h[2].w);                  \
    hi_.z = pk2(h[3].x, h[3].y); hi_.w = pk2(h[3].z, h[3].w);                  \
    *(uint4*)(&ring[slot][sdst])     = sswap ? hi_ : lo_;                      \
    *(uint4*)(&ring[slot][sdst + 8]) = sswap ? lo_ : hi_;                      \
    } while (0)

    // ---- prologue: slabs t0-1, t0, t0+1 -> slots 0,1,2 ----
    {
        float4 h[4];
        STAGE_LOAD(t0 - 1, h); STAGE_WRITE(0, h);
        STAGE_LOAD(t0,     h); STAGE_WRITE(1, h);
        STAGE_LOAD(t0 + 1, h); STAGE_WRITE(2, h);
    }
    __syncthreads();

    // hoisted epilogue constants
    const int col = wid * 16 + lr;                     // epiA column
    const float bvc = bias[col];
    const int cg = tid & 15, rb = tid >> 4;            // epiB decode
    float tv[2][8];
    #pragma unroll
    for (int j = 0; j < 2; ++j) {
        const int a = j * 32 + rb;
        const float* tp = tsum + ((size_t)(b * 64 + a)) * 128 + cg * 8;
        const float4 t0v = *(const float4*)tp, t1v = *(const float4*)(tp + 4);
        tv[j][0] = t0v.x; tv[j][1] = t0v.y; tv[j][2] = t0v.z; tv[j][3] = t0v.w;
        tv[j][4] = t1v.x; tv[j][5] = t1v.y; tv[j][6] = t1v.z; tv[j][7] = t1v.w;
    }

    #pragma unroll
    for (int ti = 0; ti < 8; ++ti) {
        const int t = t0 + ti;
        float4 h[4];
        if (ti < 7) STAGE_LOAD(t + 2, h);              // issue early (T14)

        f32x4 acc[4];
        #pragma unroll
        for (int mi = 0; mi < 4; ++mi) acc[mi] = (f32x4)0.f;

        #pragma unroll
        for (int d = 0; d < 3; ++d) {
            const int slot = (ti + d) & 3;
            #pragma unroll
            for (int g = 0; g < 4; ++g) {
                bf16x8 bq, af[4];
                bq = *(const bf16x8*)(wp + (size_t)((((d * 4 + g) * 8) + wid) * 64 + lane) * 8);
                #pragma unroll
                for (int mi = 0; mi < 4; ++mi) {
                    const int row = mi * 16 + lr;
                    af[mi] = *(const bf16x8*)(&ring[slot][row * 128 + (((g * 4 + lg) ^ (row & 7)) * 8)]);
                }
                #pragma unroll
                for (int mi = 0; mi < 4; ++mi)
                    acc[mi] = __builtin_amdgcn_mfma_f32_16x16x32_bf16(af[mi], bq, acc[mi], 0, 0, 0);
            }
        }

        // epiA: y = acc + bias -> yb (swizzled)
        #pragma unroll
        for (int mi = 0; mi < 4; ++mi)
            #pragma unroll
            for (int j = 0; j < 4; ++j) {
                const int a = mi * 16 + lg * 4 + j;
                yb[a * 128 + (col ^ ((a & 7) << 3))] = (uint16_t)f2bf(acc[mi][j] + bvc);
            }

        if (ti < 7) STAGE_WRITE((ti + 3) & 3, h);      // write late

        __syncthreads();                               // yb + new slab visible

        // epiB: out = relu((asum + tsum - y)*inv + x)
        {
            const float inv = 0.07254762501100116f;
            const float* ap = asum + ((size_t)(b * 128 + t)) * 128 + cg * 8;
            const float4 as0 = *(const float4*)ap, as1 = *(const float4*)(ap + 4);
            const float av[8] = {as0.x, as0.y, as0.z, as0.w, as1.x, as1.y, as1.z, as1.w};
            const int cslot = (ti + 1) & 3;            // center slab (x at time t)
            #pragma unroll
            for (int j = 0; j < 2; ++j) {
                const int a = j * 32 + rb;
                const int el = (cg ^ (a & 7)) * 8;     // a&7 < 8: bit3 of cg preserved
                const uint4 yv = *(const uint4*)(&yb[a * 128 + el]);
                const uint4 xv = *(const uint4*)(&ring[cslot][a * 128 + el]);
                float yy[8], xx[8];
                yy[0] = bf2f(yv.x & 0xFFFFu); yy[1] = bf2f(yv.x >> 16);
                yy[2] = bf2f(yv.y & 0xFFFFu); yy[3] = bf2f(yv.y >> 16);
                yy[4] = bf2f(yv.z & 0xFFFFu); yy[5] = bf2f(yv.z >> 16);
                yy[6] = bf2f(yv.w & 0xFFFFu); yy[7] = bf2f(yv.w >> 16);
                xx[0] = bf2f(xv.x & 0xFFFFu); xx[1] = bf2f(xv.x >> 16);
                xx[2] = bf2f(xv.y & 0xFFFFu); xx[3] = bf2f(xv.y >> 16);
                xx[4] = bf2f(xv.z & 0xFFFFu); xx[5] = bf2f(xv.z >> 16);
                xx[6] = bf2f(xv.w & 0xFFFFu); xx[7] = bf2f(xv.w >> 16);
                float o[8];
                #pragma unroll
                for (int i = 0; i < 8; ++i) {
                    const float gg = (av[i] + tv[j][i] - yy[i]) * inv + xx[i];
                    o[i] = gg > 0.f ? gg : 0.f;
                }
                float* op = out + ((size_t)((b * 128 + t) * 64 + a)) * 128 + cg * 8;
                *(float4*)op       = make_float4(o[0], o[1], o[2], o[3]);
                *(float4*)(op + 4) = make_float4(o[4], o[5], o[6], o[7]);
            }
        }
        __syncthreads();                               // epiB reads done before next epiA/stage
    }

#undef STAGE_LOAD
#undef STAGE_WRITE
}

extern "C" void kernel_launch(void* const* d_in, const int* in_sizes, int n_in,
                              void* d_out, int out_size, void* d_ws, size_t ws_size,
                              hipStream_t stream) {
    const float* x    = (const float*)d_in[0];
    const float* W    = (const float*)d_in[1];
    const float* bias = (const float*)d_in[2];
    float* out = (float*)d_out;

    // ws layout (~22.1 MB):
    //   wp      49152 bf16               :     98,304
    //   xa16    [32][130][128] bf16      :  1,064,960
    //   xt_part [32][16][64][128] f32    : 16,777,216
    //   xt      [2048][128] f32          :  1,048,576
    //   asum    [32][128][128] f32       :  2,097,152
    //   tsum    [32][64][128] f32        :  1,048,576
    char* ws = (char*)d_ws;
    uint16_t* wp    = (uint16_t*)(ws);
    uint16_t* xa16  = (uint16_t*)(ws + 98304);
    float* xt_part  = (float*)(ws + 98304 + 1064960);
    float* xt       = (float*)(ws + 98304 + 1064960 + 16777216);
    float* asum     = (float*)(ws + 98304 + 1064960 + 16777216 + 1048576);
    float* tsum     = (float*)(ws + 98304 + 1064960 + 16777216 + 1048576 + 2097152);

    red_kernel  <<<704, 256, 0, stream>>>(x, xa16, xt_part, W, wp);   // reductions + wpack
    xtr_kernel  <<<128, 256, 0, stream>>>(xt_part, xt);
    sums_kernel <<<48,  256, 0, stream>>>(xa16, xt, x, wp, bias, asum, tsum);
    conv_kernel <<<512, 512, 0, stream>>>(x, wp, bias, asum, tsum, out);
}

// Round 14
// 109.763 us; speedup vs baseline: 1.1739x; 1.1739x over previous
//
#include <hip/hip_runtime.h>
#include <hip/hip_bf16.h>
#include <stdint.h>

// B=32, L=128, A=64, C=128, KT=3.  scale = sqrt(190), inv = 1/sqrt(190).
// Linearity: agent_sum(y) = conv(sum_a x) + 64*bias ; time_sum(y) = W0*(S-x127)+W1*S+W2*(S-x0)+128*bias.
// No x16 intermediate: conv reg-stages fp32 x (L3-hot) -> bf16 LDS directly.
// R14: conversions via hip_bf16 casts -> packed v_cvt_pk_bf16_f32 (was 4-op bit-twiddle RNE).

typedef __attribute__((ext_vector_type(8))) short bf16x8;
typedef __attribute__((ext_vector_type(4))) float f32x4;

__device__ __forceinline__ uint32_t f2bf(float f) {
    union { __hip_bfloat16 b; uint16_t u; } cv;
    cv.b = __float2bfloat16(f);
    return (uint32_t)cv.u;
}
__device__ __forceinline__ float bf2f(uint32_t h) {
    union { uint32_t u; float f; } v; v.u = h << 16; return v.f;
}
__device__ __forceinline__ uint32_t pk2(float lo, float hi) {
    union { __hip_bfloat162 b; uint32_t u; } cv;
    cv.b = __float22bfloat162_rn(make_float2(lo, hi));
    return cv.u;
}

// red: block (b,g) g<16 covers 8 t's.  xa16[b][t+1][ci] = bf16(sum_a x) (+ zero guards),
// xt_part[b][g][a][ci] = sum_{t in g} x.  Blocks >= 512 pack W into MFMA B-fragment order.
__global__ __launch_bounds__(256) void red_kernel(
    const float* __restrict__ x, uint16_t* __restrict__ xa16, float* __restrict__ xt_part,
    const float* __restrict__ W, uint16_t* __restrict__ wp)
{
    const int tid = threadIdx.x;
    const int bid = blockIdx.x;
    if (bid >= 512) {                        // wpack: 192 blocks
        int o = (bid - 512) * 256 + tid;     // 49152 exact
        int i = o & 7, lane = (o >> 3) & 63, nt = (o >> 9) & 7, ks = (o >> 12) & 3, d = o >> 14;
        int ci = ks * 32 + (lane >> 4) * 8 + i;
        int co = nt * 16 + (lane & 15);
        wp[o] = (uint16_t)f2bf(W[(co * 128 + ci) * 3 + d]);
        return;
    }
    const int b = bid >> 4, g = bid & 15;
    const int ci8 = (tid & 15) * 8, ag = tid >> 4;      // a = ag*4 + r
    __shared__ float red[16][128];

    float xtl[4][8];
    #pragma unroll
    for (int r = 0; r < 4; ++r)
        #pragma unroll
        for (int j = 0; j < 8; ++j) xtl[r][j] = 0.f;

    #pragma unroll
    for (int ti = 0; ti < 8; ++ti) {
        const int t = g * 8 + ti;
        const float* xr = x + ((size_t)(b * 128 + t) * 64) * 128;
        float s[8];
        #pragma unroll
        for (int j = 0; j < 8; ++j) s[j] = 0.f;
        #pragma unroll
        for (int r = 0; r < 4; ++r) {
            const int a = ag * 4 + r;
            const float4 v0 = *(const float4*)(xr + a * 128 + ci8);
            const float4 v1 = *(const float4*)(xr + a * 128 + ci8 + 4);
            s[0] += v0.x; s[1] += v0.y; s[2] += v0.z; s[3] += v0.w;
            s[4] += v1.x; s[5] += v1.y; s[6] += v1.z; s[7] += v1.w;
            xtl[r][0] += v0.x; xtl[r][1] += v0.y; xtl[r][2] += v0.z; xtl[r][3] += v0.w;
            xtl[r][4] += v1.x; xtl[r][5] += v1.y; xtl[r][6] += v1.z; xtl[r][7] += v1.w;
        }
        *(float4*)&red[ag][ci8]     = make_float4(s[0], s[1], s[2], s[3]);
        *(float4*)&red[ag][ci8 + 4] = make_float4(s[4], s[5], s[6], s[7]);
        __syncthreads();
        if (tid < 128) {
            float v = 0.f;
            #pragma unroll
            for (int i = 0; i < 16; ++i) v += red[i][tid];
            xa16[(size_t)(b * 130 + t + 1) * 128 + tid] = (uint16_t)f2bf(v);
        }
        __syncthreads();
    }
    if (g == 0 && tid < 16)
        *(uint4*)(xa16 + (size_t)(b * 130) * 128 + tid * 8) = make_uint4(0, 0, 0, 0);
    if (g == 15 && tid < 16)
        *(uint4*)(xa16 + (size_t)(b * 130 + 129) * 128 + tid * 8) = make_uint4(0, 0, 0, 0);
    #pragma unroll
    for (int r = 0; r < 4; ++r) {
        float* p = xt_part + (((size_t)(b * 16 + g) * 64 + ag * 4 + r) * 128) + ci8;
        *(float4*)p       = make_float4(xtl[r][0], xtl[r][1], xtl[r][2], xtl[r][3]);
        *(float4*)(p + 4) = make_float4(xtl[r][4], xtl[r][5], xtl[r][6], xtl[r][7]);
    }
}

// xt[row][ci] = sum_g xt_part[b][g][a][ci]   (row = b*64+a)
__global__ __launch_bounds__(256) void xtr_kernel(
    const float* __restrict__ xt_part, float* __restrict__ xt)
{
    const int idx = blockIdx.x * 256 + threadIdx.x;   // 128 blocks: 32768 = 2048 x 16
    const int row = idx >> 4, ci8 = (idx & 15) * 8;
    const int b = row >> 6, a = row & 63;
    float s[8];
    #pragma unroll
    for (int j = 0; j < 8; ++j) s[j] = 0.f;
    #pragma unroll
    for (int g2 = 0; g2 < 16; ++g2) {
        const float* p = xt_part + (((size_t)(b * 16 + g2) * 64 + a) * 128) + ci8;
        const float4 v0 = *(const float4*)p;
        const float4 v1 = *(const float4*)(p + 4);
        s[0] += v0.x; s[1] += v0.y; s[2] += v0.z; s[3] += v0.w;
        s[4] += v1.x; s[5] += v1.y; s[6] += v1.z; s[7] += v1.w;
    }
    float* q = xt + (size_t)row * 128 + ci8;
    *(float4*)q       = make_float4(s[0], s[1], s[2], s[3]);
    *(float4*)(q + 4) = make_float4(s[4], s[5], s[6], s[7]);
}

// Combined small-GEMM kernel: blocks 0..31 -> asum (per b), blocks 32..47 -> tsum (128 rows each).
__global__ __launch_bounds__(256, 2) void sums_kernel(
    const uint16_t* __restrict__ xa16, const float* __restrict__ xt,
    const float* __restrict__ x, const uint16_t* __restrict__ wp,
    const float* __restrict__ bias, float* __restrict__ asum, float* __restrict__ tsum)
{
    __shared__ __align__(16) uint16_t slab[130 * 128];
    const int tid = threadIdx.x;
    const int lane = tid & 63, wid = tid >> 6;
    const int wm = wid >> 1, wn = wid & 1;
    const int lr = lane & 15, lg = lane >> 4;
    f32x4 acc[4][4];
    #pragma unroll
    for (int mi = 0; mi < 4; ++mi)
        #pragma unroll
        for (int ni = 0; ni < 4; ++ni) acc[mi][ni] = (f32x4)0.f;

    if (blockIdx.x < 32) {
        const int b = blockIdx.x;
        #pragma unroll
        for (int it = 0; it < 9; ++it) {
            const int gg = it * 256 + tid;
            if (gg < 2080) {
                const int row = gg >> 4, sp = gg & 15;
                const int sl = sp ^ (row & 7);
                *(uint4*)(slab + gg * 8) =
                    *(const uint4*)(xa16 + (size_t)(b * 130 + row) * 128 + sl * 8);
            }
        }
        __syncthreads();
        #pragma unroll
        for (int g = 0; g < 4; ++g)
            #pragma unroll
            for (int d = 0; d < 3; ++d) {
                bf16x8 bq[4], af[4];
                #pragma unroll
                for (int ni = 0; ni < 4; ++ni)
                    bq[ni] = *(const bf16x8*)(wp + (size_t)((((d * 4 + g) * 8) + wn * 4 + ni) * 64 + lane) * 8);
                #pragma unroll
                for (int mi = 0; mi < 4; ++mi) {
                    const int row = wm * 64 + mi * 16 + lr + d;
                    af[mi] = *(const bf16x8*)(slab + row * 128 + ((g * 4 + lg) ^ (row & 7)) * 8);
                }
                #pragma unroll
                for (int mi = 0; mi < 4; ++mi)
                    #pragma unroll
                    for (int ni = 0; ni < 4; ++ni)
                        acc[mi][ni] = __builtin_amdgcn_mfma_f32_16x16x32_bf16(af[mi], bq[ni], acc[mi][ni], 0, 0, 0);
            }
        #pragma unroll
        for (int ni = 0; ni < 4; ++ni) {
            const int col = wn * 64 + ni * 16 + lr;
            const float bv = 64.f * bias[col];
            #pragma unroll
            for (int mi = 0; mi < 4; ++mi)
                #pragma unroll
                for (int j = 0; j < 4; ++j) {
                    const int t = wm * 64 + mi * 16 + lg * 4 + j;
                    asum[((size_t)b * 128 + t) * 128 + col] = acc[mi][ni][j] + bv;
                }
        }
        return;
    }

    const int bid = blockIdx.x - 32;
    const int r = tid >> 1, h = tid & 1;
    const int grow = bid * 128 + r, sb = grow >> 6, sa = grow & 63;
    #pragma unroll
    for (int d = 0; d < 3; ++d) {
        {
            const float* Sp = xt + (size_t)grow * 128 + h * 64;
            const float* Ep = x + ((size_t)((sb * 128 + (d == 0 ? 127 : 0)) * 64 + sa)) * 128 + h * 64;
            #pragma unroll
            for (int k = 0; k < 8; ++k) {
                float4 f0 = *(const float4*)(Sp + k * 8);
                float4 f1 = *(const float4*)(Sp + k * 8 + 4);
                if (d != 1) {
                    const float4 e0 = *(const float4*)(Ep + k * 8);
                    const float4 e1 = *(const float4*)(Ep + k * 8 + 4);
                    f0.x -= e0.x; f0.y -= e0.y; f0.z -= e0.z; f0.w -= e0.w;
                    f1.x -= e1.x; f1.y -= e1.y; f1.z -= e1.z; f1.w -= e1.w;
                }
                uint4 o;
                o.x = pk2(f0.x, f0.y); o.y = pk2(f0.z, f0.w);
                o.z = pk2(f1.x, f1.y); o.w = pk2(f1.z, f1.w);
                const int sl = h * 8 + k;
                *(uint4*)(slab + r * 128 + (sl ^ (r & 7)) * 8) = o;
            }
        }
        __syncthreads();
        #pragma unroll
        for (int g = 0; g < 4; ++g) {
            bf16x8 bq[4], af[4];
            #pragma unroll
            for (int ni = 0; ni < 4; ++ni)
                bq[ni] = *(const bf16x8*)(wp + (size_t)((((d * 4 + g) * 8) + wn * 4 + ni) * 64 + lane) * 8);
            #pragma unroll
            for (int mi = 0; mi < 4; ++mi) {
                const int row = wm * 64 + mi * 16 + lr;
                af[mi] = *(const bf16x8*)(slab + row * 128 + ((g * 4 + lg) ^ (row & 7)) * 8);
            }
            #pragma unroll
            for (int mi = 0; mi < 4; ++mi)
                #pragma unroll
                for (int ni = 0; ni < 4; ++ni)
                    acc[mi][ni] = __builtin_amdgcn_mfma_f32_16x16x32_bf16(af[mi], bq[ni], acc[mi][ni], 0, 0, 0);
        }
        __syncthreads();
    }
    #pragma unroll
    for (int ni = 0; ni < 4; ++ni) {
        const int col = wn * 64 + ni * 16 + lr;
        const float bv = 128.f * bias[col];
        #pragma unroll
        for (int mi = 0; mi < 4; ++mi)
            #pragma unroll
            for (int j = 0; j < 4; ++j) {
                const int rg = bid * 128 + wm * 64 + mi * 16 + lg * 4 + j;
                tsum[(size_t)rg * 128 + col] = acc[mi][ni][j] + bv;
            }
    }
}

// Fused conv + epilogue: one block per (b, t), 512 threads / 8 waves (each a 16-co slice).
// Reg-stages fp32 x (L3-hot) -> bf16 into slab (linear dest, pre-swizzled source granule).
__global__ __launch_bounds__(512, 6) void conv_kernel(
    const float* __restrict__ x, const uint16_t* __restrict__ wp,
    const float* __restrict__ bias, const float* __restrict__ asum,
    const float* __restrict__ tsum, float* __restrict__ out)
{
    __shared__ __align__(16) uint16_t slab[2][192 * 64];   // 48 KB
    const int tid = threadIdx.x;
    // XCD swizzle: consecutive logical t-blocks land on the same XCD (4096 = 8*512)
    const int raw = blockIdx.x;
    const int bid = (raw & 7) * 512 + (raw >> 3);        // b*128 + t
    const int b = bid >> 7, t = bid & 127;
    const int lane = tid & 63, wid = tid >> 6;           // wid 0..7
    const int lr = lane & 15, lg = lane >> 4;

    f32x4 acc[4];
    #pragma unroll
    for (int mi = 0; mi < 4; ++mi) acc[mi] = (f32x4)0.f;

    // stage chunk c (192 rows x 64 ci): wave stages 24 rows (3 sub-steps of 8 rows).
    // LDS dest linear (conflict-free ds_write_b128); source granule pre-swizzled:
    // slot (lane&7) of row holds logical granule (lane&7)^(row&7).  row&7 == lane>>3.
#define STAGE(c) do {                                                          \
    _Pragma("unroll")                                                          \
    for (int k = 0; k < 3; ++k) {                                              \
        const int ro  = lane >> 3;                                             \
        const int row = wid * 24 + k * 8 + ro;                                 \
        const int gl  = (lane & 7) ^ ro;                                       \
        const int tloc = t + (row >> 6) - 1;                                   \
        uint4 o4 = make_uint4(0, 0, 0, 0);                                     \
        if ((unsigned)tloc < 128u) {                                           \
            const float* s_ = x +                                              \
                ((size_t)((b * 128 + tloc) * 64 + (row & 63))) * 128 +         \
                (c) * 64 + gl * 8;                                             \
            const float4 v0 = *(const float4*)s_;                              \
            const float4 v1 = *(const float4*)(s_ + 4);                        \
            o4.x = pk2(v0.x, v0.y); o4.y = pk2(v0.z, v0.w);                    \
            o4.z = pk2(v1.x, v1.y); o4.w = pk2(v1.z, v1.w);                    \
        }                                                                      \
        *(uint4*)(&slab[c][wid * 1536 + k * 512 + lane * 8]) = o4;             \
    } } while (0)

#define MFMA_CHUNK(c) do {                                                     \
    _Pragma("unroll")                                                          \
    for (int d = 0; d < 3; ++d)                                                \
        _Pragma("unroll")                                                      \
        for (int g2 = 0; g2 < 2; ++g2) {                                       \
            const int ks = (c) * 2 + g2;                                       \
            bf16x8 bq, af[4];                                                  \
            bq = *(const bf16x8*)(wp +                                         \
                (size_t)((((d * 4 + ks) * 8) + wid) * 64 + lane) * 8);         \
            _Pragma("unroll")                                                  \
            for (int mi = 0; mi < 4; ++mi) {                                   \
                const int row = d * 64 + mi * 16 + lr;                         \
                af[mi] = *(const bf16x8*)(&slab[c][row * 64 +                  \
                    (((g2 * 4 + lg) ^ (row & 7)) * 8)]);                       \
            }                                                                  \
            _Pragma("unroll")                                                  \
            for (int mi = 0; mi < 4; ++mi)                                     \
                acc[mi] = __builtin_amdgcn_mfma_f32_16x16x32_bf16(             \
                    af[mi], bq, acc[mi], 0, 0, 0);                             \
        } } while (0)

    STAGE(0);
    __syncthreads();          // slab[0] ready
    STAGE(1);                 // loads overlap MFMA(0) issue below
    MFMA_CHUNK(0);
    __syncthreads();          // slab[1] ready
    MFMA_CHUNK(1);
    __syncthreads();          // all reads done before bounce overwrites rows 0..63

#undef STAGE
#undef MFMA_CHUNK

    // ---- epilogue A: y = acc + bias -> bf16 bounce into rows 0..63 of slab[col>>6] ----
    {
        const int col = wid * 16 + lr;                   // co 0..127
        const float bv = bias[col];
        const int cbuf = col >> 6, cl = col & 63;
        #pragma unroll
        for (int mi = 0; mi < 4; ++mi)
            #pragma unroll
            for (int j = 0; j < 4; ++j) {
                const int a = mi * 16 + lg * 4 + j;
                slab[cbuf][a * 64 + (cl ^ ((a & 7) << 3))] = (uint16_t)f2bf(acc[mi][j] + bv);
            }
    }
    __syncthreads();

    // ---- epilogue B: out = relu((asum + tsum - y)*inv + x) ----
    // y: slab[cbuf] rows 0..63; x: slab[cbuf] rows 64..127 (center t, both ci halves in LDS).
    {
        const float inv = 0.07254762501100116f;
        const int cg = tid & 15, rb = tid >> 4;              // rb 0..31
        const int cbuf = cg >> 3, cl8 = (cg & 7) * 8;
        const float* ap = asum + ((size_t)(b * 128 + t)) * 128 + cg * 8;
        const float4 as0 = *(const float4*)ap, as1 = *(const float4*)(ap + 4);
        const float av[8] = {as0.x, as0.y, as0.z, as0.w, as1.x, as1.y, as1.z, as1.w};
        #pragma unroll
        for (int j = 0; j < 2; ++j) {
            const int a = j * 32 + rb;
            const int swz = cl8 ^ ((a & 7) << 3);
            const uint4 yv = *(const uint4*)(&slab[cbuf][a * 64 + swz]);
            const uint4 xv = *(const uint4*)(&slab[cbuf][(64 + a) * 64 + swz]);
            const float* tp = tsum + ((size_t)(b * 64 + a)) * 128 + cg * 8;
            const float4 ts0 = *(const float4*)tp, ts1 = *(const float4*)(tp + 4);
            float yy[8], xx[8];
            yy[0] = bf2f(yv.x & 0xFFFFu); yy[1] = bf2f(yv.x >> 16);
            yy[2] = bf2f(yv.y & 0xFFFFu); yy[3] = bf2f(yv.y >> 16);
            yy[4] = bf2f(yv.z & 0xFFFFu); yy[5] = bf2f(yv.z >> 16);
            yy[6] = bf2f(yv.w & 0xFFFFu); yy[7] = bf2f(yv.w >> 16);
            xx[0] = bf2f(xv.x & 0xFFFFu); xx[1] = bf2f(xv.x >> 16);
            xx[2] = bf2f(xv.y & 0xFFFFu); xx[3] = bf2f(xv.y >> 16);
            xx[4] = bf2f(xv.z & 0xFFFFu); xx[5] = bf2f(xv.z >> 16);
            xx[6] = bf2f(xv.w & 0xFFFFu); xx[7] = bf2f(xv.w >> 16);
            const float tv[8] = {ts0.x, ts0.y, ts0.z, ts0.w, ts1.x, ts1.y, ts1.z, ts1.w};
            float o[8];
            #pragma unroll
            for (int i = 0; i < 8; ++i) {
                const float gg = (av[i] + tv[i] - yy[i]) * inv + xx[i];
                o[i] = gg > 0.f ? gg : 0.f;
            }
            float* op = out + ((size_t)((b * 128 + t) * 64 + a)) * 128 + cg * 8;
            *(float4*)op       = make_float4(o[0], o[1], o[2], o[3]);
            *(float4*)(op + 4) = make_float4(o[4], o[5], o[6], o[7]);
        }
    }
}

extern "C" void kernel_launch(void* const* d_in, const int* in_sizes, int n_in,
                              void* d_out, int out_size, void* d_ws, size_t ws_size,
                              hipStream_t stream) {
    const float* x    = (const float*)d_in[0];
    const float* W    = (const float*)d_in[1];
    const float* bias = (const float*)d_in[2];
    float* out = (float*)d_out;

    // ws layout (~22.1 MB):
    //   wp      49152 bf16               :     98,304
    //   xa16    [32][130][128] bf16      :  1,064,960
    //   xt_part [32][16][64][128] f32    : 16,777,216
    //   xt      [2048][128] f32          :  1,048,576
    //   asum    [32][128][128] f32       :  2,097,152
    //   tsum    [32][64][128] f32        :  1,048,576
    char* ws = (char*)d_ws;
    uint16_t* wp    = (uint16_t*)(ws);
    uint16_t* xa16  = (uint16_t*)(ws + 98304);
    float* xt_part  = (float*)(ws + 98304 + 1064960);
    float* xt       = (float*)(ws + 98304 + 1064960 + 16777216);
    float* asum     = (float*)(ws + 98304 + 1064960 + 16777216 + 1048576);
    float* tsum     = (float*)(ws + 98304 + 1064960 + 16777216 + 1048576 + 2097152);

    red_kernel  <<<704,  256, 0, stream>>>(x, xa16, xt_part, W, wp);   // reductions + wpack
    xtr_kernel  <<<128,  256, 0, stream>>>(xt_part, xt);
    sums_kernel <<<48,   256, 0, stream>>>(xa16, xt, x, wp, bias, asum, tsum);
    conv_kernel <<<4096, 512, 0, stream>>>(x, wp, bias, asum, tsum, out);
}